// Round 14
// baseline (244.184 us; speedup 1.0000x reference)
//
#include <hip/hip_runtime.h>
#include <hip/hip_bf16.h>
#include <stdint.h>

// VQ-VAE vector quantizer for MI355X (gfx950)
// z: [32768,256] f32, codebook: [256,8192] f32
// out: z_q [8388608] f32, indices-as-f32 [32768], loss [1]
//
// Round 14: DIAGNOSTIC. Exact round-9 pipeline (159.4 us total, scan 124 us)
// + k_scan_ns ablation probe launched LAST: identical scan minus in-loop
// global_load_lds staging + vmcnt (B read from step-0 buffer, deterministic).
// Probe overwrites cand after refine consumed it -> harness output unchanged;
// every replay's k_scan fully rewrites cand before refine. Probe duration
// (rocprof table / total delta) isolates staging's marginal cost.

#define DEVINL __device__ __forceinline__

typedef int   intx4 __attribute__((ext_vector_type(4)));

#define NROWS   32768
#define DIMS    256
#define NCODES  8192
#define KMIN    ((int)0x80000000)

// ---------------- helpers ----------------
DEVINL int q8(float v, float s) {
  int q = __float2int_rn(v * s);
  return min(127, max(-127, q));
}
DEVINL unsigned pk4(float4 v, float s) {
  int a = q8(v.x, s), b = q8(v.y, s), c = q8(v.z, s), d = q8(v.w, s);
  return (unsigned)(a & 255) | ((unsigned)(b & 255) << 8) |
         ((unsigned)(c & 255) << 16) | ((unsigned)(d & 255) << 24);
}
DEVINL void gload_lds16(const void* g, void* lds) {
  __builtin_amdgcn_global_load_lds(
      (const __attribute__((address_space(1))) uint32_t*)(uintptr_t)g,
      (__attribute__((address_space(3))) uint32_t*)(uint32_t)(uintptr_t)lds,
      16, 0, 0);
}

// ---------------- K1: scaled norms of quantized codes ----------------
// nrm[j] = rint( (25/254) * sum_d q8(c[d][j]*127)^2 )
__global__ void k_nrm(const float* __restrict__ cb, int* __restrict__ nrm) {
  __shared__ int p[256];
  int j = blockIdx.x * 32 + (threadIdx.x & 31);
  int seg = threadIdx.x >> 5;
  int s = 0;
  for (int i = 0; i < 32; ++i) {
    int q = q8(cb[(size_t)(seg * 32 + i) * NCODES + j], 127.0f);
    s += q * q;
  }
  p[threadIdx.x] = s;
  __syncthreads();
  if (threadIdx.x < 32) {
    int t = 0;
    for (int k = 0; k < 8; ++k) t += p[k * 32 + threadIdx.x];
    nrm[j] = (int)rintf((25.0f / 254.0f) * (float)t);
  }
}

// ---------------- K2: f32 transpose cbTf[j][d] (for exact refine) ----------
__global__ void k_transpose(const float* __restrict__ cb, float* __restrict__ cbTf) {
  __shared__ float t[64][65];
  int j0 = blockIdx.x * 64, d0 = blockIdx.y * 64;
  int tx = threadIdx.x & 63, ty = threadIdx.x >> 6;
  #pragma unroll
  for (int i = 0; i < 16; ++i) {
    int dl = i * 4 + ty;
    t[dl][tx] = cb[(size_t)(d0 + dl) * NCODES + j0 + tx];
  }
  __syncthreads();
  #pragma unroll
  for (int i = 0; i < 16; ++i) {
    int jl = i * 4 + ty;
    cbTf[(size_t)(j0 + jl) * DIMS + d0 + tx] = t[tx][jl];
  }
}

// ---------------- K3: i8 fragment image ----------------
__global__ void k_image(const float* __restrict__ cbTf, uint4* __restrict__ img) {
  int g = blockIdx.x * 256 + threadIdx.x;     // 0..131071
  int step = g >> 11;                          // 0..63
  int r = g & 2047;
  int wc = r >> 9, cf = (r >> 6) & 7, lgr = (r >> 4) & 3, l15 = r & 15;
  int tile = step >> 2, chunk = step & 3;
  int j = tile * 512 + wc * 128 + cf * 16 + l15;
  int d = chunk * 64 + lgr * 16;
  const float4* s4 = (const float4*)(cbTf + (size_t)j * DIMS + d);
  uint4 o;
  o.x = pk4(s4[0], 127.0f); o.y = pk4(s4[1], 127.0f);
  o.z = pk4(s4[2], 127.0f); o.w = pk4(s4[3], 127.0f);
  img[g] = o;
}

// ---------------- K4: i8 MFMA scan (exact round-9) -------------------------
__global__ __launch_bounds__(512, 2)
void k_scan(const float* __restrict__ z, const int* __restrict__ nrm,
            const uint4* __restrict__ img, int2* __restrict__ cand) {
  __shared__ char smem[163840];
  char* const zb = smem;                        // 32 KB: 128 rows x 256 i8
  char* const bb = smem + 32768;                // 3 x 32 KB B buffers
  const int* const nl = (const int*)(smem + 131072);  // 32 KB nrm

  const int t = threadIdx.x;
  const int lane = t & 63;
  const int wave = t >> 6;
  const int wgr = wave >> 2;
  const int wc  = wave & 3;
  const int l15 = lane & 15;
  const int lgr = lane >> 4;
  const int brow = blockIdx.x * 128;

  #pragma unroll
  for (int i = 0; i < 4; ++i) {
    int g = t + i * 512;
    int row = g >> 4, kb = g & 15;
    const float4* src = (const float4*)(z + (size_t)(brow + row) * DIMS + kb * 16);
    uint4 o;
    o.x = pk4(src[0], 25.0f); o.y = pk4(src[1], 25.0f);
    o.z = pk4(src[2], 25.0f); o.w = pk4(src[3], 25.0f);
    int addr = row * 256 + ((kb * 16) ^ ((row & 15) << 4));
    *(uint4*)(zb + addr) = o;
  }
  #pragma unroll
  for (int i = 0; i < 4; ++i) {
    int gi = t + i * 512;
    ((uint4*)(smem + 131072))[gi] = ((const uint4*)nrm)[gi];
  }
  {
    const uint4* gsrc = img + wave * 64 + lane;
    #pragma unroll
    for (int i = 0; i < 4; ++i)
      gload_lds16(gsrc + i * 512, bb + (i * 512 + wave * 64) * 16);
  }

  int k1[16], k2[16];
  #pragma unroll
  for (int i = 0; i < 16; ++i) { k1[i] = KMIN; k2[i] = KMIN; }

  __syncthreads();

  intx4 acc[4][8];
  int b_cur = 0, b_nxt = 1;

  #pragma unroll 1
  for (int s = 0; s < 64; ++s) {
    const int tile = s >> 2, chunk = s & 3;

    if (s < 63) {
      const uint4* gsrc = img + (size_t)(s + 1) * 2048 + wave * 64 + lane;
      char* dst = bb + b_nxt * 32768;
      #pragma unroll
      for (int i = 0; i < 4; ++i)
        gload_lds16(gsrc + i * 512, dst + (i * 512 + wave * 64) * 16);
      asm volatile("s_waitcnt vmcnt(4)" ::: "memory");
    } else {
      asm volatile("s_waitcnt vmcnt(0)" ::: "memory");
    }
    __builtin_amdgcn_s_barrier();

    const char* cbuf = bb + b_cur * 32768;

    if (chunk == 0) {
      #pragma unroll
      for (int cf = 0; cf < 8; ++cf) {
        int h = -nl[tile * 512 + wc * 128 + cf * 16 + l15];
        #pragma unroll
        for (int rf = 0; rf < 4; ++rf) acc[rf][cf] = intx4{h, h, h, h};
      }
    }

    intx4 a[4], b[8];
    #pragma unroll
    for (int rf = 0; rf < 4; ++rf) {
      int m = wgr * 64 + rf * 16 + l15;
      int by = (chunk * 64 + lgr * 16) ^ ((m & 15) << 4);
      a[rf] = *(const intx4*)(zb + m * 256 + by);
    }
    #pragma unroll
    for (int cf = 0; cf < 8; ++cf)
      b[cf] = *(const intx4*)(cbuf + (wc * 512 + cf * 64 + lane) * 16);

    #pragma unroll
    for (int rf = 0; rf < 4; ++rf)
      #pragma unroll
      for (int cf = 0; cf < 8; ++cf)
        acc[rf][cf] = __builtin_amdgcn_mfma_i32_16x16x64_i8(a[rf], b[cf], acc[rf][cf], 0, 0, 0);

    if (chunk == 3) {
      const int jinvb = 8191 - (tile * 512 + wc * 128 + l15);
      #pragma unroll
      for (int rf = 0; rf < 4; ++rf)
        #pragma unroll
        for (int cf = 0; cf < 8; ++cf) {
          int jinv = jinvb - cf * 16;
          #pragma unroll
          for (int r = 0; r < 4; ++r) {
            int si = rf * 4 + r;
            int k = ((acc[rf][cf][r] >> 5) << 13) + jinv;
            int t1 = max(k1[si], k);
            int t2 = min(k1[si], k);
            k1[si] = t1;
            k2[si] = max(k2[si], t2);
          }
        }
    }

    b_cur = b_nxt;
    b_nxt = (b_nxt == 2) ? 0 : b_nxt + 1;
  }

  #pragma unroll
  for (int rf = 0; rf < 4; ++rf)
    #pragma unroll
    for (int r = 0; r < 4; ++r) {
      int row = brow + wgr * 64 + rf * 16 + lgr * 4 + r;
      int si = rf * 4 + r;
      cand[(size_t)row * 64 + wc * 16 + l15] = make_int2(k1[si], k2[si]);
    }
}

// ---------------- K4b: ABLATION PROBE — scan minus in-loop staging ---------
// Identical to k_scan except: no in-loop global_load_lds, no vmcnt waits;
// B always read from buffer 0 (staged in prologue, deterministic). Launched
// AFTER k_refine; overwrites cand (safe: fully rewritten by k_scan next call).
__global__ __launch_bounds__(512, 2)
void k_scan_ns(const float* __restrict__ z, const int* __restrict__ nrm,
               const uint4* __restrict__ img, int2* __restrict__ cand) {
  __shared__ char smem[163840];
  char* const zb = smem;
  char* const bb = smem + 32768;
  const int* const nl = (const int*)(smem + 131072);

  const int t = threadIdx.x;
  const int lane = t & 63;
  const int wave = t >> 6;
  const int wgr = wave >> 2;
  const int wc  = wave & 3;
  const int l15 = lane & 15;
  const int lgr = lane >> 4;
  const int brow = blockIdx.x * 128;

  #pragma unroll
  for (int i = 0; i < 4; ++i) {
    int g = t + i * 512;
    int row = g >> 4, kb = g & 15;
    const float4* src = (const float4*)(z + (size_t)(brow + row) * DIMS + kb * 16);
    uint4 o;
    o.x = pk4(src[0], 25.0f); o.y = pk4(src[1], 25.0f);
    o.z = pk4(src[2], 25.0f); o.w = pk4(src[3], 25.0f);
    int addr = row * 256 + ((kb * 16) ^ ((row & 15) << 4));
    *(uint4*)(zb + addr) = o;
  }
  #pragma unroll
  for (int i = 0; i < 4; ++i) {
    int gi = t + i * 512;
    ((uint4*)(smem + 131072))[gi] = ((const uint4*)nrm)[gi];
  }
  {
    const uint4* gsrc = img + wave * 64 + lane;
    #pragma unroll
    for (int i = 0; i < 4; ++i)
      gload_lds16(gsrc + i * 512, bb + (i * 512 + wave * 64) * 16);
  }

  int k1[16], k2[16];
  #pragma unroll
  for (int i = 0; i < 16; ++i) { k1[i] = KMIN; k2[i] = KMIN; }

  __syncthreads();

  intx4 acc[4][8];

  #pragma unroll 1
  for (int s = 0; s < 64; ++s) {
    const int tile = s >> 2, chunk = s & 3;

    __builtin_amdgcn_s_barrier();   // keep per-step barrier (core structure)

    const char* cbuf = bb;          // always buffer 0 (no staging)

    if (chunk == 0) {
      #pragma unroll
      for (int cf = 0; cf < 8; ++cf) {
        int h = -nl[tile * 512 + wc * 128 + cf * 16 + l15];
        #pragma unroll
        for (int rf = 0; rf < 4; ++rf) acc[rf][cf] = intx4{h, h, h, h};
      }
    }

    intx4 a[4], b[8];
    #pragma unroll
    for (int rf = 0; rf < 4; ++rf) {
      int m = wgr * 64 + rf * 16 + l15;
      int by = (chunk * 64 + lgr * 16) ^ ((m & 15) << 4);
      a[rf] = *(const intx4*)(zb + m * 256 + by);
    }
    #pragma unroll
    for (int cf = 0; cf < 8; ++cf)
      b[cf] = *(const intx4*)(cbuf + (wc * 512 + cf * 64 + lane) * 16);

    #pragma unroll
    for (int rf = 0; rf < 4; ++rf)
      #pragma unroll
      for (int cf = 0; cf < 8; ++cf)
        acc[rf][cf] = __builtin_amdgcn_mfma_i32_16x16x64_i8(a[rf], b[cf], acc[rf][cf], 0, 0, 0);

    if (chunk == 3) {
      const int jinvb = 8191 - (tile * 512 + wc * 128 + l15);
      #pragma unroll
      for (int rf = 0; rf < 4; ++rf)
        #pragma unroll
        for (int cf = 0; cf < 8; ++cf) {
          int jinv = jinvb - cf * 16;
          #pragma unroll
          for (int r = 0; r < 4; ++r) {
            int si = rf * 4 + r;
            int k = ((acc[rf][cf][r] >> 5) << 13) + jinv;
            int t1 = max(k1[si], k);
            int t2 = min(k1[si], k);
            k1[si] = t1;
            k2[si] = max(k2[si], t2);
          }
        }
    }
  }

  #pragma unroll
  for (int rf = 0; rf < 4; ++rf)
    #pragma unroll
    for (int r = 0; r < 4; ++r) {
      int row = brow + wgr * 64 + rf * 16 + lgr * 4 + r;
      int si = rf * 4 + r;
      cand[(size_t)row * 64 + wc * 16 + l15] = make_int2(k1[si], k2[si]);
    }
}

// ---------------- K5: exact fp64 refine (top-5) + outputs + loss partials ----
__global__ __launch_bounds__(512)
void k_refine(const float* __restrict__ z, const float* __restrict__ cbTf,
              const int2* __restrict__ cand, float* __restrict__ zq,
              float* __restrict__ oidx, double* __restrict__ parts) {
  __shared__ double lsum[8];
  int lane = threadIdx.x & 63, wave = threadIdx.x >> 6;
  int row = blockIdx.x * 8 + wave;

  float4 z4 = ((const float4*)(z + (size_t)row * DIMS))[lane];
  int2 kp = cand[(size_t)row * 64 + lane];
  int ka = kp.x, kb = kp.y;

  double bd = 1e300; int bj = -1; float4 bc = {0.f, 0.f, 0.f, 0.f};
  for (int s = 0; s < 5; ++s) {
    int km = max(ka, kb);
    #pragma unroll
    for (int m = 1; m < 64; m <<= 1) km = max(km, __shfl_xor(km, m, 64));
    int j = 8191 - (km & 8191);
    if (ka == km) ka = KMIN; else if (kb == km) kb = KMIN;

    float4 c4 = ((const float4*)(cbTf + (size_t)j * DIMS))[lane];
    double dx = (double)z4.x - (double)c4.x;
    double dy = (double)z4.y - (double)c4.y;
    double dzv = (double)z4.z - (double)c4.z;
    double dw = (double)z4.w - (double)c4.w;
    double d = dx * dx + dy * dy + dzv * dzv + dw * dw;
    #pragma unroll
    for (int m = 1; m < 64; m <<= 1) d += __shfl_xor(d, m, 64);

    bool bt = (d < bd) || (d == bd && j < bj);   // wave-uniform
    if (bt) { bd = d; bj = j; bc = c4; }
  }

  ((float4*)(zq + (size_t)row * DIMS))[lane] = bc;
  if (lane == 0) oidx[row] = (float)bj;

  double lx = (double)bc.x - (double)z4.x;
  double ly = (double)bc.y - (double)z4.y;
  double lz = (double)bc.z - (double)z4.z;
  double lw = (double)bc.w - (double)z4.w;
  double l = lx * lx + ly * ly + lz * lz + lw * lw;
  #pragma unroll
  for (int m = 1; m < 64; m <<= 1) l += __shfl_xor(l, m, 64);
  if (lane == 0) lsum[wave] = l;
  __syncthreads();
  if (threadIdx.x == 0) {
    double s = 0;
    for (int i = 0; i < 8; ++i) s += lsum[i];
    parts[blockIdx.x] = s;
  }
}

// ---------------- K6: loss finalize ----------------
__global__ void k_finish(const double* __restrict__ parts, float* __restrict__ out) {
  __shared__ double s[256];
  double a = 0;
  for (int i = threadIdx.x; i < 4096; i += 256) a += parts[i];
  s[threadIdx.x] = a;
  __syncthreads();
  for (int w = 128; w; w >>= 1) {
    if (threadIdx.x < w) s[threadIdx.x] += s[threadIdx.x + w];
    __syncthreads();
  }
  if (threadIdx.x == 0) out[0] = (float)(1.25 * s[0] / 8388608.0);
}

// ---------------- launch ----------------
extern "C" void kernel_launch(void* const* d_in, const int* in_sizes, int n_in,
                              void* d_out, int out_size, void* d_ws, size_t ws_size,
                              hipStream_t stream) {
  const float* zin = (const float*)d_in[0];
  const float* cb  = (const float*)d_in[1];
  float* out = (float*)d_out;

  char* w = (char*)d_ws;
  int*    nrm   = (int*)w;                                          // 32 KB
  float*  cbTf  = (float*)(w + 32768);                              // 8 MB
  char*   imgb  = w + 32768 + 8388608;                              // 2 MB
  int2*   cand  = (int2*)(w + 32768 + 8388608 + 2097152);           // 16 MB
  double* parts = (double*)(w + 32768 + 8388608 + 2097152 + 16777216); // 32 KB

  float* zq_out   = out;
  float* idx_out  = out + 8388608;
  float* loss_out = out + 8388608 + 32768;

  k_nrm<<<dim3(256), dim3(256), 0, stream>>>(cb, nrm);
  k_transpose<<<dim3(128, 4), dim3(256), 0, stream>>>(cb, cbTf);
  k_image<<<dim3(512), dim3(256), 0, stream>>>(cbTf, (uint4*)imgb);
  k_scan<<<dim3(256), dim3(512), 0, stream>>>(zin, nrm, (const uint4*)imgb, cand);
  k_refine<<<dim3(4096), dim3(512), 0, stream>>>(zin, cbTf, cand, zq_out, idx_out, parts);
  k_finish<<<dim3(1), dim3(256), 0, stream>>>(parts, loss_out);
  // diagnostic probe: scan minus staging; overwrites cand AFTER refine
  k_scan_ns<<<dim3(256), dim3(512), 0, stream>>>(zin, nrm, (const uint4*)imgb, cand);
}

// Round 16
// 236.798 us; speedup vs baseline: 1.0312x; 1.0312x over previous
//
#include <hip/hip_runtime.h>
#include <hip/hip_bf16.h>
#include <stdint.h>

// VQ-VAE vector quantizer for MI355X (gfx950)
// z: [32768,256] f32, codebook: [256,8192] f32
// out: z_q [8388608] f32, indices-as-f32 [32768], loss [1]
//
// Round 16: clean-room acc ping-pong (r15 retry, isolated). r12 geometry
// (512 blocks x 64 rows, 8 waves wgr2 x wc4, rf2, i8 16x16x64, double-
// buffered B via global_load_lds). Two acc banks; tile t's MFMAs overlap
// tile t-1's key-fold (independent regs -> VALU under MFMA). Written as a
// typed lambda (no macro), tiles 0-1 peeled so in-loop doFold is constant,
// fold at chunks 1-2 (clear of chunk-0 init). REFINE = r9's proven top-5
// fp64 (r15's refine-3 cut reverted). Score math / key packing / bucket
// partition / cand layout bit-identical to passing rounds 9-12.

#define DEVINL __device__ __forceinline__

typedef int   intx4 __attribute__((ext_vector_type(4)));

#define NROWS   32768
#define DIMS    256
#define NCODES  8192
#define KMIN    ((int)0x80000000)

// ---------------- helpers ----------------
DEVINL int q8(float v, float s) {
  int q = __float2int_rn(v * s);
  return min(127, max(-127, q));
}
DEVINL unsigned pk4(float4 v, float s) {
  int a = q8(v.x, s), b = q8(v.y, s), c = q8(v.z, s), d = q8(v.w, s);
  return (unsigned)(a & 255) | ((unsigned)(b & 255) << 8) |
         ((unsigned)(c & 255) << 16) | ((unsigned)(d & 255) << 24);
}
DEVINL void gload_lds16(const void* g, void* lds) {
  __builtin_amdgcn_global_load_lds(
      (const __attribute__((address_space(1))) uint32_t*)(uintptr_t)g,
      (__attribute__((address_space(3))) uint32_t*)(uint32_t)(uintptr_t)lds,
      16, 0, 0);
}

// ---------------- K1: scaled norms of quantized codes ----------------
// nrm[j] = rint( (25/254) * sum_d q8(c[d][j]*127)^2 )
//   so (dot - nrm) == 3175 * (z.c - ||c||^2/2) in quantized units.
__global__ void k_nrm(const float* __restrict__ cb, int* __restrict__ nrm) {
  __shared__ int p[256];
  int j = blockIdx.x * 32 + (threadIdx.x & 31);
  int seg = threadIdx.x >> 5;
  int s = 0;
  for (int i = 0; i < 32; ++i) {
    int q = q8(cb[(size_t)(seg * 32 + i) * NCODES + j], 127.0f);
    s += q * q;
  }
  p[threadIdx.x] = s;
  __syncthreads();
  if (threadIdx.x < 32) {
    int t = 0;
    for (int k = 0; k < 8; ++k) t += p[k * 32 + threadIdx.x];
    nrm[j] = (int)rintf((25.0f / 254.0f) * (float)t);
  }
}

// ---------------- K2: f32 transpose cbTf[j][d] (for exact refine) ----------
__global__ void k_transpose(const float* __restrict__ cb, float* __restrict__ cbTf) {
  __shared__ float t[64][65];
  int j0 = blockIdx.x * 64, d0 = blockIdx.y * 64;
  int tx = threadIdx.x & 63, ty = threadIdx.x >> 6;
  #pragma unroll
  for (int i = 0; i < 16; ++i) {
    int dl = i * 4 + ty;
    t[dl][tx] = cb[(size_t)(d0 + dl) * NCODES + j0 + tx];
  }
  __syncthreads();
  #pragma unroll
  for (int i = 0; i < 16; ++i) {
    int jl = i * 4 + ty;
    cbTf[(size_t)(j0 + jl) * DIMS + d0 + tx] = t[tx][jl];
  }
}

// ---------------- K3: i8 fragment image ----------------
// granule g (16B = 16 K-bytes) = [step 64][wc 4][cf 8][lgr 4][l15 16]
//   step = tile*4+chunk; code j = tile*512 + wc*128 + cf*16 + l15
//   dims d = chunk*64 + lgr*16 .. +16  (linear K within granule)
__global__ void k_image(const float* __restrict__ cbTf, uint4* __restrict__ img) {
  int g = blockIdx.x * 256 + threadIdx.x;     // 0..131071
  int step = g >> 11;                          // 0..63
  int r = g & 2047;
  int wc = r >> 9, cf = (r >> 6) & 7, lgr = (r >> 4) & 3, l15 = r & 15;
  int tile = step >> 2, chunk = step & 3;
  int j = tile * 512 + wc * 128 + cf * 16 + l15;
  int d = chunk * 64 + lgr * 16;
  const float4* s4 = (const float4*)(cbTf + (size_t)j * DIMS + d);
  uint4 o;
  o.x = pk4(s4[0], 127.0f); o.y = pk4(s4[1], 127.0f);
  o.z = pk4(s4[2], 127.0f); o.w = pk4(s4[3], 127.0f);
  img[g] = o;
}

// ---------------- K4: i8 MFMA scan, clean ping-pong fold overlap -----------
// 512 blocks x 512 threads. Block: 64 rows x 8192 codes, 64 steps of K=64.
// Waves: wgr(2) x wc(4); wave-tile 32 rows x 128 codes; 16x16x64 rf2 x cf8.
// LDS: z 16KB (i8 swizzled) | B 2x32KB double buffer.
__global__ __launch_bounds__(512, 2)
void k_scan(const float* __restrict__ z, const int* __restrict__ nrm,
            const uint4* __restrict__ img, int2* __restrict__ cand) {
  __shared__ char smem[81920];
  char* const zb = smem;                        // 16 KB: 64 rows x 256 i8
  char* const bb = smem + 16384;                // 2 x 32 KB B buffers

  const int t = threadIdx.x;
  const int lane = t & 63;
  const int wave = t >> 6;
  const int wgr = wave >> 2;                    // row half 0..1
  const int wc  = wave & 3;                     // code group 0..3
  const int l15 = lane & 15;
  const int lgr = lane >> 4;
  const int brow = blockIdx.x * 64;

  // stage z: 1024 granules; pos = (kblk*16)^((row&15)<<4)
  #pragma unroll
  for (int i = 0; i < 2; ++i) {
    int g = t + i * 512;
    int row = g >> 4, kb = g & 15;
    const float4* src = (const float4*)(z + (size_t)(brow + row) * DIMS + kb * 16);
    uint4 o;
    o.x = pk4(src[0], 25.0f); o.y = pk4(src[1], 25.0f);
    o.z = pk4(src[2], 25.0f); o.w = pk4(src[3], 25.0f);
    int addr = row * 256 + ((kb * 16) ^ ((row & 15) << 4));
    *(uint4*)(zb + addr) = o;
  }
  // stage B step 0 into buf0
  {
    const uint4* gsrc = img + wave * 64 + lane;
    #pragma unroll
    for (int i = 0; i < 4; ++i)
      gload_lds16(gsrc + i * 512, bb + (i * 512 + wave * 64) * 16);
  }

  int k1[8], k2[8];
  #pragma unroll
  for (int i = 0; i < 8; ++i) { k1[i] = KMIN; k2[i] = KMIN; }

  __syncthreads();   // z visible; step-0 B resident (full drain, once)

  intx4 accA[2][8], accB[2][8];

  // one tile: 4 chunks; optional fold of (tileIdx-1) from prv at chunks 1,2
  auto tbody = [&](int tileIdx, intx4 (&cur)[2][8], intx4 (&prv)[2][8],
                   bool doFold) {
    #pragma unroll
    for (int chunk = 0; chunk < 4; ++chunk) {
      const int s = tileIdx * 4 + chunk;
      if (s > 0) {
        asm volatile("s_waitcnt vmcnt(0)" ::: "memory");  // step-s loads in
        __builtin_amdgcn_s_barrier();
      }
      if (s < 63) {
        // issue step s+1 after the barrier; buf[(s+1)&1] has no readers
        const uint4* gsrc = img + (size_t)(s + 1) * 2048 + wave * 64 + lane;
        char* dst = bb + ((s + 1) & 1) * 32768;
        #pragma unroll
        for (int i = 0; i < 4; ++i)
          gload_lds16(gsrc + i * 512, dst + (i * 512 + wave * 64) * 16);
      }
      const char* cbuf = bb + (s & 1) * 32768;

      if (chunk == 0) {
        #pragma unroll
        for (int cf = 0; cf < 8; ++cf) {
          int h = -nrm[tileIdx * 512 + wc * 128 + cf * 16 + l15];
          cur[0][cf] = intx4{h, h, h, h};
          cur[1][cf] = intx4{h, h, h, h};
        }
      }

      intx4 a0, a1;
      {
        int by = (chunk * 64 + lgr * 16) ^ (l15 << 4);
        a0 = *(const intx4*)(zb + (wgr * 32 + l15) * 256 + by);
        a1 = *(const intx4*)(zb + (wgr * 32 + 16 + l15) * 256 + by);
      }
      #pragma unroll
      for (int cf = 0; cf < 8; ++cf) {
        intx4 b = *(const intx4*)(cbuf + (wc * 512 + cf * 64 + lane) * 16);
        cur[0][cf] = __builtin_amdgcn_mfma_i32_16x16x64_i8(a0, b, cur[0][cf], 0, 0, 0);
        cur[1][cf] = __builtin_amdgcn_mfma_i32_16x16x64_i8(a1, b, cur[1][cf], 0, 0, 0);
      }

      if (doFold && (chunk == 1 || chunk == 2)) {
        const int jb = 8191 - ((tileIdx - 1) * 512 + wc * 128 + l15);
        #pragma unroll
        for (int rf = 0; rf < 2; ++rf)
          #pragma unroll
          for (int co = 0; co < 4; ++co) {
            const int cf = (chunk - 1) * 4 + co;
            const int jinv = jb - cf * 16;
            #pragma unroll
            for (int r = 0; r < 4; ++r) {
              const int si = rf * 4 + r;
              int kk = ((prv[rf][cf][r] >> 5) << 13) + jinv;
              int u1 = max(k1[si], kk);
              int u2 = min(k1[si], kk);
              k1[si] = u1;
              k2[si] = max(k2[si], u2);
            }
          }
      }
    }
  };

  // peel tiles 0,1 so the loop's doFold is compile-constant true
  tbody(0, accA, accB, false);
  tbody(1, accB, accA, true);          // folds tile 0 (accA)
  #pragma unroll 1
  for (int tp = 1; tp < 8; ++tp) {
    tbody(2 * tp,     accA, accB, true);   // folds tile 2tp-1 (accB)
    tbody(2 * tp + 1, accB, accA, true);   // folds tile 2tp   (accA)
  }
  // final fold: tile 15 (accB), all 8 cf
  {
    const int jb = 8191 - (15 * 512 + wc * 128 + l15);
    #pragma unroll
    for (int rf = 0; rf < 2; ++rf)
      #pragma unroll
      for (int cf = 0; cf < 8; ++cf) {
        const int jinv = jb - cf * 16;
        #pragma unroll
        for (int r = 0; r < 4; ++r) {
          const int si = rf * 4 + r;
          int kk = ((accB[rf][cf][r] >> 5) << 13) + jinv;
          int u1 = max(k1[si], kk);
          int u2 = min(k1[si], kk);
          k1[si] = u1;
          k2[si] = max(k2[si], u2);
        }
      }
  }

  // write candidates: [row][64 buckets] int2
  #pragma unroll
  for (int rf = 0; rf < 2; ++rf)
    #pragma unroll
    for (int r = 0; r < 4; ++r) {
      int row = brow + wgr * 32 + rf * 16 + lgr * 4 + r;
      int si = rf * 4 + r;
      cand[(size_t)row * 64 + wc * 16 + l15] = make_int2(k1[si], k2[si]);
    }
}

// ---------------- K5: exact fp64 refine (top-5) + outputs + loss partials ----
__global__ __launch_bounds__(512)
void k_refine(const float* __restrict__ z, const float* __restrict__ cbTf,
              const int2* __restrict__ cand, float* __restrict__ zq,
              float* __restrict__ oidx, double* __restrict__ parts) {
  __shared__ double lsum[8];
  int lane = threadIdx.x & 63, wave = threadIdx.x >> 6;
  int row = blockIdx.x * 8 + wave;

  float4 z4 = ((const float4*)(z + (size_t)row * DIMS))[lane];
  int2 kp = cand[(size_t)row * 64 + lane];
  int ka = kp.x, kb = kp.y;

  double bd = 1e300; int bj = -1; float4 bc = {0.f, 0.f, 0.f, 0.f};
  for (int s = 0; s < 5; ++s) {
    int km = max(ka, kb);
    #pragma unroll
    for (int m = 1; m < 64; m <<= 1) km = max(km, __shfl_xor(km, m, 64));
    int j = 8191 - (km & 8191);
    if (ka == km) ka = KMIN; else if (kb == km) kb = KMIN;

    float4 c4 = ((const float4*)(cbTf + (size_t)j * DIMS))[lane];
    double dx = (double)z4.x - (double)c4.x;
    double dy = (double)z4.y - (double)c4.y;
    double dzv = (double)z4.z - (double)c4.z;
    double dw = (double)z4.w - (double)c4.w;
    double d = dx * dx + dy * dy + dzv * dzv + dw * dw;
    #pragma unroll
    for (int m = 1; m < 64; m <<= 1) d += __shfl_xor(d, m, 64);

    bool bt = (d < bd) || (d == bd && j < bj);   // wave-uniform
    if (bt) { bd = d; bj = j; bc = c4; }
  }

  ((float4*)(zq + (size_t)row * DIMS))[lane] = bc;
  if (lane == 0) oidx[row] = (float)bj;

  double lx = (double)bc.x - (double)z4.x;
  double ly = (double)bc.y - (double)z4.y;
  double lz = (double)bc.z - (double)z4.z;
  double lw = (double)bc.w - (double)z4.w;
  double l = lx * lx + ly * ly + lz * lz + lw * lw;
  #pragma unroll
  for (int m = 1; m < 64; m <<= 1) l += __shfl_xor(l, m, 64);
  if (lane == 0) lsum[wave] = l;
  __syncthreads();
  if (threadIdx.x == 0) {
    double s = 0;
    for (int i = 0; i < 8; ++i) s += lsum[i];
    parts[blockIdx.x] = s;
  }
}

// ---------------- K6: loss finalize ----------------
__global__ void k_finish(const double* __restrict__ parts, float* __restrict__ out) {
  __shared__ double s[256];
  double a = 0;
  for (int i = threadIdx.x; i < 4096; i += 256) a += parts[i];
  s[threadIdx.x] = a;
  __syncthreads();
  for (int w = 128; w; w >>= 1) {
    if (threadIdx.x < w) s[threadIdx.x] += s[threadIdx.x + w];
    __syncthreads();
  }
  if (threadIdx.x == 0) out[0] = (float)(1.25 * s[0] / 8388608.0);
}

// ---------------- launch ----------------
extern "C" void kernel_launch(void* const* d_in, const int* in_sizes, int n_in,
                              void* d_out, int out_size, void* d_ws, size_t ws_size,
                              hipStream_t stream) {
  const float* zin = (const float*)d_in[0];
  const float* cb  = (const float*)d_in[1];
  float* out = (float*)d_out;

  char* w = (char*)d_ws;
  int*    nrm   = (int*)w;                                          // 32 KB
  float*  cbTf  = (float*)(w + 32768);                              // 8 MB
  char*   imgb  = w + 32768 + 8388608;                              // 2 MB
  int2*   cand  = (int2*)(w + 32768 + 8388608 + 2097152);           // 16 MB
  double* parts = (double*)(w + 32768 + 8388608 + 2097152 + 16777216); // 32 KB

  float* zq_out   = out;
  float* idx_out  = out + 8388608;
  float* loss_out = out + 8388608 + 32768;

  k_nrm<<<dim3(256), dim3(256), 0, stream>>>(cb, nrm);
  k_transpose<<<dim3(128, 4), dim3(256), 0, stream>>>(cb, cbTf);
  k_image<<<dim3(512), dim3(256), 0, stream>>>(cbTf, (uint4*)imgb);
  k_scan<<<dim3(512), dim3(512), 0, stream>>>(zin, nrm, (const uint4*)imgb, cand);
  k_refine<<<dim3(4096), dim3(512), 0, stream>>>(zin, cbTf, cand, zq_out, idx_out, parts);
  k_finish<<<dim3(1), dim3(256), 0, stream>>>(parts, loss_out);
}

// Round 17
// 162.263 us; speedup vs baseline: 1.5049x; 1.4593x over previous
//
#include <hip/hip_runtime.h>
#include <hip/hip_bf16.h>
#include <stdint.h>

// VQ-VAE vector quantizer for MI355X (gfx950)
// z: [32768,256] f32, codebook: [256,8192] f32
// out: z_q [8388608] f32, indices-as-f32 [32768], loss [1]
//
// Round 17: BARRIER-FREE scan. r10 geometry (512 blocks x 64 rows, 4 waves
// = 4 code groups, i8 16x16x64, acc[4][8]) but B staging is WAVE-PRIVATE:
// each wave global_load_lds's only its own wc slice (8KB/step) into a
// private 2x8KB double buffer -> no inter-wave data sharing -> zero
// main-loop barriers; the wave's own vmcnt(8) orders loads. Waves free-run
// and de-phase. nrm folded at score time (keys algebraically identical).
// Score math / key packing / bucket partition / cand layout / top-5 fp64
// refine bit-identical to passing rounds 9-12.

#define DEVINL __device__ __forceinline__

typedef int   intx4 __attribute__((ext_vector_type(4)));

#define NROWS   32768
#define DIMS    256
#define NCODES  8192
#define KMIN    ((int)0x80000000)

// ---------------- helpers ----------------
DEVINL int q8(float v, float s) {
  int q = __float2int_rn(v * s);
  return min(127, max(-127, q));
}
DEVINL unsigned pk4(float4 v, float s) {
  int a = q8(v.x, s), b = q8(v.y, s), c = q8(v.z, s), d = q8(v.w, s);
  return (unsigned)(a & 255) | ((unsigned)(b & 255) << 8) |
         ((unsigned)(c & 255) << 16) | ((unsigned)(d & 255) << 24);
}
DEVINL void gload_lds16(const void* g, void* lds) {
  __builtin_amdgcn_global_load_lds(
      (const __attribute__((address_space(1))) uint32_t*)(uintptr_t)g,
      (__attribute__((address_space(3))) uint32_t*)(uint32_t)(uintptr_t)lds,
      16, 0, 0);
}

// ---------------- K1: scaled norms of quantized codes ----------------
// nrm[j] = rint( (25/254) * sum_d q8(c[d][j]*127)^2 )
//   so (dot - nrm) == 3175 * (z.c - ||c||^2/2) in quantized units.
__global__ void k_nrm(const float* __restrict__ cb, int* __restrict__ nrm) {
  __shared__ int p[256];
  int j = blockIdx.x * 32 + (threadIdx.x & 31);
  int seg = threadIdx.x >> 5;
  int s = 0;
  for (int i = 0; i < 32; ++i) {
    int q = q8(cb[(size_t)(seg * 32 + i) * NCODES + j], 127.0f);
    s += q * q;
  }
  p[threadIdx.x] = s;
  __syncthreads();
  if (threadIdx.x < 32) {
    int t = 0;
    for (int k = 0; k < 8; ++k) t += p[k * 32 + threadIdx.x];
    nrm[j] = (int)rintf((25.0f / 254.0f) * (float)t);
  }
}

// ---------------- K2: f32 transpose cbTf[j][d] (for exact refine) ----------
__global__ void k_transpose(const float* __restrict__ cb, float* __restrict__ cbTf) {
  __shared__ float t[64][65];
  int j0 = blockIdx.x * 64, d0 = blockIdx.y * 64;
  int tx = threadIdx.x & 63, ty = threadIdx.x >> 6;
  #pragma unroll
  for (int i = 0; i < 16; ++i) {
    int dl = i * 4 + ty;
    t[dl][tx] = cb[(size_t)(d0 + dl) * NCODES + j0 + tx];
  }
  __syncthreads();
  #pragma unroll
  for (int i = 0; i < 16; ++i) {
    int jl = i * 4 + ty;
    cbTf[(size_t)(j0 + jl) * DIMS + d0 + tx] = t[tx][jl];
  }
}

// ---------------- K3: i8 fragment image ----------------
// granule g (16B = 16 K-bytes) = [step 64][wc 4][cf 8][lgr 4][l15 16]
//   step = tile*4+chunk; code j = tile*512 + wc*128 + cf*16 + l15
//   dims d = chunk*64 + lgr*16 .. +16  (linear K within granule)
__global__ void k_image(const float* __restrict__ cbTf, uint4* __restrict__ img) {
  int g = blockIdx.x * 256 + threadIdx.x;     // 0..131071
  int step = g >> 11;                          // 0..63
  int r = g & 2047;
  int wc = r >> 9, cf = (r >> 6) & 7, lgr = (r >> 4) & 3, l15 = r & 15;
  int tile = step >> 2, chunk = step & 3;
  int j = tile * 512 + wc * 128 + cf * 16 + l15;
  int d = chunk * 64 + lgr * 16;
  const float4* s4 = (const float4*)(cbTf + (size_t)j * DIMS + d);
  uint4 o;
  o.x = pk4(s4[0], 127.0f); o.y = pk4(s4[1], 127.0f);
  o.z = pk4(s4[2], 127.0f); o.w = pk4(s4[3], 127.0f);
  img[g] = o;
}

// ---------------- K4: i8 MFMA scan, barrier-free wave-private staging ------
// 512 blocks x 256 threads. Block: 64 rows x 8192 codes, 64 steps of K=64.
// 4 waves = 4 code groups; wave-tile 64 rows x 128 codes; 16x16x64 rf4 x cf8.
// LDS: z 16KB (i8 swizzled, shared read-only) | per-wave B 2x8KB = 80KB.
// No main-loop barriers: each wave stages/reads only its own buffers;
// uniform vmcnt(8) per step orders its own loads.
__global__ __launch_bounds__(256, 2)
void k_scan(const float* __restrict__ z, const int* __restrict__ nrm,
            const uint4* __restrict__ img, int2* __restrict__ cand) {
  __shared__ char smem[81920];
  char* const zb = smem;                        // 16 KB: 64 rows x 256 i8

  const int t = threadIdx.x;
  const int lane = t & 63;
  const int wave = t >> 6;                      // code group 0..3
  const int l15 = lane & 15;
  const int lgr = lane >> 4;
  const int brow = blockIdx.x * 64;
  char* const mybb = smem + 16384 + wave * 16384;  // private 2 x 8 KB

  // stage z: 1024 granules (16B each); pos = (kblk*16)^((row&15)<<4)
  #pragma unroll
  for (int i = 0; i < 4; ++i) {
    int g = t + i * 256;
    int row = g >> 4, kb = g & 15;
    const float4* src = (const float4*)(z + (size_t)(brow + row) * DIMS + kb * 16);
    uint4 o;
    o.x = pk4(src[0], 25.0f); o.y = pk4(src[1], 25.0f);
    o.z = pk4(src[2], 25.0f); o.w = pk4(src[3], 25.0f);
    int addr = row * 256 + ((kb * 16) ^ ((row & 15) << 4));
    *(uint4*)(zb + addr) = o;
  }
  // stage B step 0 into my buf0 (wave-private slice: wc*512 granules)
  {
    const uint4* gsrc = img + wave * 512 + lane;
    #pragma unroll
    for (int i = 0; i < 8; ++i)
      gload_lds16(gsrc + i * 64, mybb + i * 1024);
  }

  // per row-slot top-2 packed keys
  int k1[16], k2[16];
  #pragma unroll
  for (int i = 0; i < 16; ++i) { k1[i] = KMIN; k2[i] = KMIN; }

  __syncthreads();   // z visible to all waves (also drains step-0 loads)

  intx4 acc[4][8];

  #pragma unroll 1
  for (int s = 0; s < 64; ++s) {
    const int tile = s >> 2, chunk = s & 3;

    // nrm for fold (chunk 3): issue BEFORE the B prefetch so the uniform
    // vmcnt(8) below covers them; compiler re-waits before use.
    int nv[8];
    if (chunk == 3) {
      #pragma unroll
      for (int cf = 0; cf < 8; ++cf)
        nv[cf] = nrm[tile * 512 + wave * 128 + cf * 16 + l15];
    }

    // issue next step's private staging; then wait: all but the 8 newest
    // loads done => current buffer (and any nrm) resident. No barrier.
    if (s < 63) {
      const uint4* gsrc = img + (size_t)(s + 1) * 2048 + wave * 512 + lane;
      char* dst = mybb + ((s + 1) & 1) * 8192;
      #pragma unroll
      for (int i = 0; i < 8; ++i)
        gload_lds16(gsrc + i * 64, dst + i * 1024);
    }
    asm volatile("s_waitcnt vmcnt(8)" ::: "memory");

    const char* cbuf = mybb + (s & 1) * 8192;

    // acc init: zeros (nrm folded at score time; keys identical)
    if (chunk == 0) {
      #pragma unroll
      for (int cf = 0; cf < 8; ++cf)
        #pragma unroll
        for (int rf = 0; rf < 4; ++rf) acc[rf][cf] = intx4{0, 0, 0, 0};
    }

    // fragments
    intx4 a[4], b[8];
    #pragma unroll
    for (int rf = 0; rf < 4; ++rf) {
      int m = rf * 16 + l15;
      int by = (chunk * 64 + lgr * 16) ^ (l15 << 4);
      a[rf] = *(const intx4*)(zb + m * 256 + by);
    }
    #pragma unroll
    for (int cf = 0; cf < 8; ++cf)
      b[cf] = *(const intx4*)(cbuf + (cf * 64 + lane) * 16);

    #pragma unroll
    for (int rf = 0; rf < 4; ++rf)
      #pragma unroll
      for (int cf = 0; cf < 8; ++cf)
        acc[rf][cf] = __builtin_amdgcn_mfma_i32_16x16x64_i8(a[rf], b[cf], acc[rf][cf], 0, 0, 0);

    // tile epilogue: fold 8 int scores/row-slot into running top-2
    if (chunk == 3) {
      const int jinvb = 8191 - (tile * 512 + wave * 128 + l15);
      #pragma unroll
      for (int rf = 0; rf < 4; ++rf)
        #pragma unroll
        for (int cf = 0; cf < 8; ++cf) {
          int jinv = jinvb - cf * 16;
          #pragma unroll
          for (int r = 0; r < 4; ++r) {
            int si = rf * 4 + r;
            int k = (((acc[rf][cf][r] - nv[cf]) >> 5) << 13) + jinv;
            int t1 = max(k1[si], k);
            int t2 = min(k1[si], k);
            k1[si] = t1;
            k2[si] = max(k2[si], t2);
          }
        }
    }
  }

  // write candidates: [row][64 buckets] int2
  #pragma unroll
  for (int rf = 0; rf < 4; ++rf)
    #pragma unroll
    for (int r = 0; r < 4; ++r) {
      int row = brow + rf * 16 + lgr * 4 + r;
      int si = rf * 4 + r;
      cand[(size_t)row * 64 + wave * 16 + l15] = make_int2(k1[si], k2[si]);
    }
}

// ---------------- K5: exact fp64 refine (top-5) + outputs + loss partials ----
__global__ __launch_bounds__(512)
void k_refine(const float* __restrict__ z, const float* __restrict__ cbTf,
              const int2* __restrict__ cand, float* __restrict__ zq,
              float* __restrict__ oidx, double* __restrict__ parts) {
  __shared__ double lsum[8];
  int lane = threadIdx.x & 63, wave = threadIdx.x >> 6;
  int row = blockIdx.x * 8 + wave;

  float4 z4 = ((const float4*)(z + (size_t)row * DIMS))[lane];
  int2 kp = cand[(size_t)row * 64 + lane];
  int ka = kp.x, kb = kp.y;

  double bd = 1e300; int bj = -1; float4 bc = {0.f, 0.f, 0.f, 0.f};
  for (int s = 0; s < 5; ++s) {
    int km = max(ka, kb);
    #pragma unroll
    for (int m = 1; m < 64; m <<= 1) km = max(km, __shfl_xor(km, m, 64));
    int j = 8191 - (km & 8191);
    if (ka == km) ka = KMIN; else if (kb == km) kb = KMIN;

    float4 c4 = ((const float4*)(cbTf + (size_t)j * DIMS))[lane];
    double dx = (double)z4.x - (double)c4.x;
    double dy = (double)z4.y - (double)c4.y;
    double dzv = (double)z4.z - (double)c4.z;
    double dw = (double)z4.w - (double)c4.w;
    double d = dx * dx + dy * dy + dzv * dzv + dw * dw;
    #pragma unroll
    for (int m = 1; m < 64; m <<= 1) d += __shfl_xor(d, m, 64);

    bool bt = (d < bd) || (d == bd && j < bj);   // wave-uniform
    if (bt) { bd = d; bj = j; bc = c4; }
  }

  ((float4*)(zq + (size_t)row * DIMS))[lane] = bc;
  if (lane == 0) oidx[row] = (float)bj;

  double lx = (double)bc.x - (double)z4.x;
  double ly = (double)bc.y - (double)z4.y;
  double lz = (double)bc.z - (double)z4.z;
  double lw = (double)bc.w - (double)z4.w;
  double l = lx * lx + ly * ly + lz * lz + lw * lw;
  #pragma unroll
  for (int m = 1; m < 64; m <<= 1) l += __shfl_xor(l, m, 64);
  if (lane == 0) lsum[wave] = l;
  __syncthreads();
  if (threadIdx.x == 0) {
    double s = 0;
    for (int i = 0; i < 8; ++i) s += lsum[i];
    parts[blockIdx.x] = s;
  }
}

// ---------------- K6: loss finalize ----------------
__global__ void k_finish(const double* __restrict__ parts, float* __restrict__ out) {
  __shared__ double s[256];
  double a = 0;
  for (int i = threadIdx.x; i < 4096; i += 256) a += parts[i];
  s[threadIdx.x] = a;
  __syncthreads();
  for (int w = 128; w; w >>= 1) {
    if (threadIdx.x < w) s[threadIdx.x] += s[threadIdx.x + w];
    __syncthreads();
  }
  if (threadIdx.x == 0) out[0] = (float)(1.25 * s[0] / 8388608.0);
}

// ---------------- launch ----------------
extern "C" void kernel_launch(void* const* d_in, const int* in_sizes, int n_in,
                              void* d_out, int out_size, void* d_ws, size_t ws_size,
                              hipStream_t stream) {
  const float* zin = (const float*)d_in[0];
  const float* cb  = (const float*)d_in[1];
  float* out = (float*)d_out;

  char* w = (char*)d_ws;
  int*    nrm   = (int*)w;                                          // 32 KB
  float*  cbTf  = (float*)(w + 32768);                              // 8 MB
  char*   imgb  = w + 32768 + 8388608;                              // 2 MB
  int2*   cand  = (int2*)(w + 32768 + 8388608 + 2097152);           // 16 MB
  double* parts = (double*)(w + 32768 + 8388608 + 2097152 + 16777216); // 32 KB

  float* zq_out   = out;
  float* idx_out  = out + 8388608;
  float* loss_out = out + 8388608 + 32768;

  k_nrm<<<dim3(256), dim3(256), 0, stream>>>(cb, nrm);
  k_transpose<<<dim3(128, 4), dim3(256), 0, stream>>>(cb, cbTf);
  k_image<<<dim3(512), dim3(256), 0, stream>>>(cbTf, (uint4*)imgb);
  k_scan<<<dim3(512), dim3(256), 0, stream>>>(zin, nrm, (const uint4*)imgb, cand);
  k_refine<<<dim3(4096), dim3(512), 0, stream>>>(zin, cbTf, cand, zq_out, idx_out, parts);
  k_finish<<<dim3(1), dim3(256), 0, stream>>>(parts, loss_out);
}